// Round 8
// baseline (218.638 us; speedup 1.0000x reference)
//
#include <hip/hip_runtime.h>
#include <hip/hip_bf16.h>
#include <stdint.h>

#define DIM   768
#define MID   256
#define HEADS 12
#define NB    64
#define NN    197
#define NT    (NB*NN)   // 12608
#define QKVC  2304      // 3*DIM
#define NCOMB 2560      // 3*DIM + MID

typedef __attribute__((ext_vector_type(4))) float f32x4;
typedef __attribute__((ext_vector_type(8))) short s8v;

__device__ __forceinline__ unsigned short f2b(float f) {
    union { float f; unsigned int u; } x; x.f = f;
    unsigned int u = x.u;
    unsigned int r = (u + 0x7FFFu + ((u >> 16) & 1u)) >> 16;
    return (unsigned short)r;
}
__device__ __forceinline__ float b2f(unsigned short s) {
    union { unsigned int u; float f; } x; x.u = ((unsigned int)s) << 16;
    return x.f;
}

__device__ __forceinline__ void gld_lds16(const void* g, void* l) {
    __builtin_amdgcn_global_load_lds(
        (const __attribute__((address_space(1))) unsigned int*)g,
        (__attribute__((address_space(3))) unsigned int*)l, 16, 0, 0);
}

// ------- merged casts: x (grid-stride) + all weights, one dispatch --------
__global__ void cast_all(const float* __restrict__ x,
                         const float* __restrict__ qkv_w,
                         const float* __restrict__ down_w,
                         const float* __restrict__ up_w,
                         const float* __restrict__ proj_w,
                         unsigned short* __restrict__ xb,
                         unsigned short* __restrict__ o_comb,
                         unsigned short* __restrict__ o_up,
                         unsigned short* __restrict__ o_proj) {
    int blk = blockIdx.x;
    if (blk < 2048) {
        const int n4 = NT * DIM / 4;
        for (int i = blk * 256 + threadIdx.x; i < n4; i += 2048 * 256) {
            float4 v = ((const float4*)x)[i];
            ushort4 o;
            o.x = f2b(v.x); o.y = f2b(v.y); o.z = f2b(v.z); o.w = f2b(v.w);
            ((ushort4*)xb)[i] = o;
        }
        return;
    }
    blk -= 2048;
    const float* in; unsigned short* out; int base;
    if (blk < 1728)      { in = qkv_w;  out = o_comb;              base = blk; }
    else if (blk < 1920) { in = down_w; out = o_comb + QKVC * DIM; base = blk - 1728; }
    else if (blk < 2304) { in = up_w;   out = o_up;                base = blk - 1920; }
    else                 { in = proj_w; out = o_proj;              base = blk - 2304; }
    int i = base * 256 + threadIdx.x;
    float4 v = ((const float4*)in)[i];
    ushort4 o;
    o.x = f2b(v.x); o.y = f2b(v.y); o.z = f2b(v.z); o.w = f2b(v.w);
    ((ushort4*)out)[i] = o;
}

// ==== 128^2 GEMM, BK=64, double-buffer, R0-verified window skeleton ========
// Per window: stage(kt+1) -> vmcnt(8) -> barrier -> 16 ds_read + 32 MFMA -> barrier.
// vmcnt BEFORE barrier (wave-local loads certified, then published) — the
// ordering R7 got wrong. 12 windows for K=768. LDS 64 KiB -> 2 blocks/CU.
// EPI 0: combined qkv+down; EPI 2: proj (fp32 out).
template<int EPI>
__global__ __launch_bounds__(256) void gemm64(
    const unsigned short* __restrict__ A,
    const unsigned short* __restrict__ W,
    const float* __restrict__ bias0,
    const float* __restrict__ bias1,
    int M, int K, int GN,
    unsigned short* __restrict__ ob0,   // qkvbuf (EPI 0)
    unsigned short* __restrict__ ob1,   // hbuf   (EPI 0)
    float* __restrict__ outf)           // fp32 out (EPI 2)
{
    __shared__ __align__(16) unsigned short lds[2][2][128 * 64];  // 64 KiB
    const int tid = threadIdx.x;
    const int l = tid & 63;
    const int w = tid >> 6;
    const int wr = w >> 1, wc = w & 1;

    const int nwg = gridDim.x;
    const int orig = blockIdx.x;
    const int q8 = nwg >> 3, r8 = nwg & 7;
    const int xcd = orig & 7, slice = orig >> 3;
    const int wgid = (xcd < r8 ? xcd * (q8 + 1)
                               : r8 * (q8 + 1) + (xcd - r8) * q8) + slice;
    const int bm = wgid / GN;
    const int bn = wgid - bm * GN;

    f32x4 acc[4][4];
#pragma unroll
    for (int m = 0; m < 4; ++m)
#pragma unroll
        for (int n = 0; n < 4; ++n)
            acc[m][n] = (f32x4){0.f, 0.f, 0.f, 0.f};

    const int KT = K >> 6;   // BK=64 windows

    // --- staging: 256 thr x 16B x 8 = 32 KiB (A+B tile); pointer-bumped ---
    const int sr = tid >> 3;                 // 0..31 (row within 32-row pass)
    const int sc = tid & 7;                  // chunk 0..7
    const int srco = ((sc ^ (sr & 7)) << 3); // pre-swizzled global chunk offset
    const int dbase = sr * 64 + sc * 8;      // linear LDS dest (elems)
    int ra0 = bm * 128 +  0 + sr; if (ra0 > M - 1) ra0 = M - 1;
    int ra1 = bm * 128 + 32 + sr; if (ra1 > M - 1) ra1 = M - 1;
    int ra2 = bm * 128 + 64 + sr; if (ra2 > M - 1) ra2 = M - 1;
    int ra3 = bm * 128 + 96 + sr; if (ra3 > M - 1) ra3 = M - 1;
    const unsigned short* pa0 = A + (size_t)ra0 * K + srco;
    const unsigned short* pa1 = A + (size_t)ra1 * K + srco;
    const unsigned short* pa2 = A + (size_t)ra2 * K + srco;
    const unsigned short* pa3 = A + (size_t)ra3 * K + srco;
    const unsigned short* pb0 = W + (size_t)(bn * 128 +  0 + sr) * K + srco;
    const unsigned short* pb1 = W + (size_t)(bn * 128 + 32 + sr) * K + srco;
    const unsigned short* pb2 = W + (size_t)(bn * 128 + 64 + sr) * K + srco;
    const unsigned short* pb3 = W + (size_t)(bn * 128 + 96 + sr) * K + srco;

    auto stage = [&](int buf) {
        gld_lds16(pa0, &lds[buf][0][dbase]);
        gld_lds16(pa1, &lds[buf][0][dbase + 32 * 64]);
        gld_lds16(pa2, &lds[buf][0][dbase + 64 * 64]);
        gld_lds16(pa3, &lds[buf][0][dbase + 96 * 64]);
        gld_lds16(pb0, &lds[buf][1][dbase]);
        gld_lds16(pb1, &lds[buf][1][dbase + 32 * 64]);
        gld_lds16(pb2, &lds[buf][1][dbase + 64 * 64]);
        gld_lds16(pb3, &lds[buf][1][dbase + 96 * 64]);
        pa0 += 64; pa1 += 64; pa2 += 64; pa3 += 64;
        pb0 += 64; pb1 += 64; pb2 += 64; pb3 += 64;
    };

    stage(0);   // prologue: tile 0 in flight

    // read-side swizzled chunks: row&7 == l&7 (row = ..x16 + (l&15))
    const int ch0 = (((l >> 4)    ) ^ (l & 7)) << 3;   // kk=0
    const int ch1 = (((l >> 4) + 4) ^ (l & 7)) << 3;   // kk=1
    int buf = 0;
    for (int kt = 0; kt < KT; ++kt) {
        if (kt + 1 < KT) {
            stage(buf ^ 1);    // tile kt+1: 8 loads in flight across the window
            asm volatile("s_waitcnt vmcnt(8)" ::: "memory");  // tile kt landed (this wave)
        } else {
            asm volatile("s_waitcnt vmcnt(0)" ::: "memory");
        }
        __builtin_amdgcn_s_barrier();            // tile kt visible to all waves
        const unsigned short* la = lds[buf][0];
        const unsigned short* lb = lds[buf][1];
#pragma unroll
        for (int kk = 0; kk < 2; ++kk) {
            const int ch = kk ? ch1 : ch0;
            s8v a[4], b[4];
#pragma unroll
            for (int m = 0; m < 4; ++m)
                a[m] = *(const s8v*)&la[(wr * 64 + m * 16 + (l & 15)) * 64 + ch];
#pragma unroll
            for (int n = 0; n < 4; ++n)
                b[n] = *(const s8v*)&lb[(wc * 64 + n * 16 + (l & 15)) * 64 + ch];
            __builtin_amdgcn_s_setprio(1);
#pragma unroll
            for (int m = 0; m < 4; ++m)
#pragma unroll
                for (int n = 0; n < 4; ++n)
                    acc[m][n] = __builtin_amdgcn_mfma_f32_16x16x32_bf16(a[m], b[n], acc[m][n], 0, 0, 0);
            __builtin_amdgcn_s_setprio(0);
        }
        __builtin_amdgcn_s_barrier();            // all waves done reading buf (WAR)
        buf ^= 1;
    }
    // last window waited vmcnt(0); sync before LDS reuse in epilogue
    __syncthreads();

    if (EPI == 0) {
        // combined qkv+down epilogue: coalesced via wave-private LDS transpose
        unsigned short* stg = ((unsigned short*)lds) + w * (16 * 68);
        const int C0 = bn * 128 + wc * 64;
        const bool ish = (C0 >= QKVC);       // block/wave-uniform (64-col granules)
#pragma unroll
        for (int mq = 0; mq < 4; ++mq) {
#pragma unroll
            for (int n = 0; n < 4; ++n) {
                int c = C0 + n * 16 + (l & 15);
                float bi = ish ? bias1[c - QKVC] : bias0[c];
                float sc2 = (c < DIM) ? 0.125f : 1.0f;
#pragma unroll
                for (int j = 0; j < 4; ++j) {
                    float v = acc[mq][n][j] + bi;
                    v = ish ? tanhf(v) : v * sc2;
                    stg[((l >> 4) * 4 + j) * 68 + n * 16 + (l & 15)] = f2b(v);
                }
            }
#pragma unroll
            for (int p = 0; p < 2; ++p) {
                int rr2 = p * 8 + (l >> 3);
                int r = bm * 128 + wr * 64 + mq * 16 + rr2;
                s8v v = *(const s8v*)&stg[rr2 * 68 + (l & 7) * 8];
                if (r < M) {
                    if (!ish) *(s8v*)&ob0[(size_t)r * QKVC + C0 + (l & 7) * 8] = v;
                    else      *(s8v*)&ob1[(size_t)r * MID + (C0 - QKVC) + (l & 7) * 8] = v;
                }
            }
        }
    } else {
#pragma unroll
        for (int n = 0; n < 4; ++n) {
            int c = bn * 128 + wc * 64 + n * 16 + (l & 15);
            float bi = bias0[c];
#pragma unroll
            for (int m = 0; m < 4; ++m) {
#pragma unroll
                for (int j = 0; j < 4; ++j) {
                    int r = bm * 128 + wr * 64 + m * 16 + (l >> 4) * 4 + j;
                    if (r >= M) continue;
                    outf[(size_t)r * DIM + c] = acc[m][n][j] + bi;
                }
            }
        }
    }
}

// ------- 128^2 GEMM, BK=32, 3-buffer 2-deep prefetch (up, K=256) -------
// EPI 1: up RMW (coalesced short8): qkvbuf[r][768+c] += 0.8*(acc+bias)
__global__ __launch_bounds__(256) void gemm_up(
    const unsigned short* __restrict__ A,
    const unsigned short* __restrict__ W,
    const float* __restrict__ bias0,
    int M, int K, int GN,
    unsigned short* __restrict__ ob0)   // qkvbuf
{
    __shared__ __align__(16) unsigned short lds[3][2][128 * 32];  // 48 KiB
    const int tid = threadIdx.x;
    const int l = tid & 63;
    const int w = tid >> 6;
    const int wr = w >> 1, wc = w & 1;

    const int nwg = gridDim.x;
    const int orig = blockIdx.x;
    const int q8 = nwg >> 3, r8 = nwg & 7;
    const int xcd = orig & 7, slice = orig >> 3;
    const int wgid = (xcd < r8 ? xcd * (q8 + 1)
                               : r8 * (q8 + 1) + (xcd - r8) * q8) + slice;
    const int bm = wgid / GN;
    const int bn = wgid - bm * GN;

    f32x4 acc[4][4];
#pragma unroll
    for (int m = 0; m < 4; ++m)
#pragma unroll
        for (int n = 0; n < 4; ++n)
            acc[m][n] = (f32x4){0.f, 0.f, 0.f, 0.f};

    const int KT = K >> 5;

    const int src = (((tid & 3) ^ ((tid >> 3) & 3)) << 3);
    const int dst = ((tid & 3) << 3);
    const int dA0 = (tid >> 2) * 32 + dst;
    const int dA1 = dA0 + 64 * 32;
    int ra0 = bm * 128 + (tid >> 2);      if (ra0 > M - 1) ra0 = M - 1;
    int ra1 = bm * 128 + 64 + (tid >> 2); if (ra1 > M - 1) ra1 = M - 1;
    const unsigned short* pa0 = A + (size_t)ra0 * K + src;
    const unsigned short* pa1 = A + (size_t)ra1 * K + src;
    const unsigned short* pb0 = W + (size_t)(bn * 128 + (tid >> 2)) * K + src;
    const unsigned short* pb1 = W + (size_t)(bn * 128 + 64 + (tid >> 2)) * K + src;

    auto stage = [&](int buf) {
        gld_lds16(pa0, &lds[buf][0][dA0]);
        gld_lds16(pb0, &lds[buf][1][dA0]);
        gld_lds16(pa1, &lds[buf][0][dA1]);
        gld_lds16(pb1, &lds[buf][1][dA1]);
        pa0 += 32; pa1 += 32; pb0 += 32; pb1 += 32;
    };

    stage(0);
    stage(1);

    const int rsl = (((l >> 4) ^ ((l >> 1) & 3)) << 3);
    int cb = 0;
    int sb = 2;
    for (int kt = 0; kt < KT; ++kt) {
        if (kt + 1 < KT) asm volatile("s_waitcnt vmcnt(4)" ::: "memory");
        else             asm volatile("s_waitcnt vmcnt(0)" ::: "memory");
        __builtin_amdgcn_s_barrier();
        asm volatile("" ::: "memory");
        if (kt + 2 < KT) stage(sb);
        const unsigned short* la = lds[cb][0];
        const unsigned short* lb = lds[cb][1];
        s8v a[4], b[4];
#pragma unroll
        for (int m = 0; m < 4; ++m)
            a[m] = *(const s8v*)&la[(wr * 64 + m * 16 + (l & 15)) * 32 + rsl];
#pragma unroll
        for (int n = 0; n < 4; ++n)
            b[n] = *(const s8v*)&lb[(wc * 64 + n * 16 + (l & 15)) * 32 + rsl];
        __builtin_amdgcn_s_setprio(1);
#pragma unroll
        for (int m = 0; m < 4; ++m)
#pragma unroll
            for (int n = 0; n < 4; ++n)
                acc[m][n] = __builtin_amdgcn_mfma_f32_16x16x32_bf16(a[m], b[n], acc[m][n], 0, 0, 0);
        __builtin_amdgcn_s_setprio(0);
        cb = (cb == 2) ? 0 : cb + 1;
        sb = (sb == 2) ? 0 : sb + 1;
    }
    __syncthreads();

    // coalesced RMW epilogue via wave-private LDS transpose
    unsigned short* stg = ((unsigned short*)lds) + w * (16 * 68);
    const int C0 = bn * 128 + wc * 64;
#pragma unroll
    for (int mq = 0; mq < 4; ++mq) {
#pragma unroll
        for (int n = 0; n < 4; ++n) {
            int c = C0 + n * 16 + (l & 15);
            float bi = bias0[c];
#pragma unroll
            for (int j = 0; j < 4; ++j)
                stg[((l >> 4) * 4 + j) * 68 + n * 16 + (l & 15)] =
                    f2b(0.8f * (acc[mq][n][j] + bi));
        }
#pragma unroll
        for (int p = 0; p < 2; ++p) {
            int rr2 = p * 8 + (l >> 3);
            int r = bm * 128 + wr * 64 + mq * 16 + rr2;
            if (r < M) {
                size_t base = (size_t)r * QKVC + DIM + C0 + (l & 7) * 8;
                s8v add = *(const s8v*)&stg[rr2 * 68 + (l & 7) * 8];
                s8v old = *(const s8v*)&ob0[base];
                s8v res;
#pragma unroll
                for (int i = 0; i < 8; ++i)
                    res[i] = (short)f2b(b2f((unsigned short)old[i]) +
                                        b2f((unsigned short)add[i]));
                *(s8v*)&ob0[base] = res;
            }
        }
    }
}

// ---------------- attention: one block per (b,h), strided qkv layout ----------------
#define NKV  224
#define VPAD 232

__global__ __launch_bounds__(256) void attn_kernel(
    const unsigned short* __restrict__ qkv,
    unsigned short* __restrict__ ob)
{
    __shared__ __align__(16) unsigned short Ks[NKV * 64];
    __shared__ __align__(16) unsigned short Vt[64 * VPAD];
    __shared__ __align__(16) unsigned short Ps[64 * VPAD];

    const int tid = threadIdx.x;
    const int l = tid & 63;
    const int w = tid >> 6;
    const int bh = blockIdx.x;
    const int b = bh / HEADS, h = bh - b * HEADS;
    const unsigned short* qp = qkv + (size_t)(b * NN) * QKVC + h * 64;
    const unsigned short* kp = qp + DIM;
    const unsigned short* vp = qp + 2 * DIM;

    const s8v zer = (s8v){0, 0, 0, 0, 0, 0, 0, 0};

    for (int e = tid; e < NKV * 8; e += 256) {
        int r = e >> 3, ch = e & 7;
        int idx = (r * 64 + ch * 8) ^ ((r & 7) << 3);
        s8v val = (r < NN) ? *(const s8v*)&kp[(size_t)r * QKVC + ch * 8] : zer;
        *(s8v*)&Ks[idx] = val;
    }
    for (int e = tid; e < NKV * 8; e += 256) {
        int r = e >> 3, ch = e & 7;
        s8v val = (r < NN) ? *(const s8v*)&vp[(size_t)r * QKVC + ch * 8] : zer;
#pragma unroll
        for (int i = 0; i < 8; ++i)
            Vt[(ch * 8 + i) * VPAD + r] = (unsigned short)val[i];
    }
    __syncthreads();

    for (int qc = 0; qc < 4; ++qc) {
        const int rbase = qc * 64 + w * 16;
        s8v aq[2];
#pragma unroll
        for (int kc = 0; kc < 2; ++kc) {
            int r = rbase + (l & 15); if (r > NN - 1) r = NN - 1;
            aq[kc] = *(const s8v*)&qp[(size_t)r * QKVC + kc * 32 + (l >> 4) * 8];
        }
        f32x4 sacc[14];
#pragma unroll
        for (int t = 0; t < 14; ++t) sacc[t] = (f32x4){0.f, 0.f, 0.f, 0.f};
#pragma unroll
        for (int t = 0; t < 14; ++t) {
            int col = t * 16 + (l & 15);
#pragma unroll
            for (int kc = 0; kc < 2; ++kc) {
                int idx = (col * 64 + kc * 32 + (l >> 4) * 8) ^ ((col & 7) << 3);
                s8v bk = *(const s8v*)&Ks[idx];
                sacc[t] = __builtin_amdgcn_mfma_f32_16x16x32_bf16(aq[kc], bk, sacc[t], 0, 0, 0);
            }
        }
        float mx[4] = {-1e30f, -1e30f, -1e30f, -1e30f};
#pragma unroll
        for (int t = 0; t < 14; ++t) {
            int col = t * 16 + (l & 15);
            if (col < NN) {
#pragma unroll
                for (int j = 0; j < 4; ++j) mx[j] = fmaxf(mx[j], sacc[t][j]);
            }
        }
#pragma unroll
        for (int j = 0; j < 4; ++j)
#pragma unroll
            for (int off = 1; off < 16; off <<= 1)
                mx[j] = fmaxf(mx[j], __shfl_xor(mx[j], off, 64));

        float sm[4] = {0.f, 0.f, 0.f, 0.f};
#pragma unroll
        for (int t = 0; t < 14; ++t) {
            int col = t * 16 + (l & 15);
#pragma unroll
            for (int j = 0; j < 4; ++j) {
                float p = (col < NN) ? __expf(sacc[t][j] - mx[j]) : 0.f;
                sm[j] += p;
                Ps[(w * 16 + (l >> 4) * 4 + j) * VPAD + col] = f2b(p);
            }
        }
#pragma unroll
        for (int j = 0; j < 4; ++j)
#pragma unroll
            for (int off = 1; off < 16; off <<= 1)
                sm[j] += __shfl_xor(sm[j], off, 64);

        f32x4 oacc[4];
#pragma unroll
        for (int n = 0; n < 4; ++n) oacc[n] = (f32x4){0.f, 0.f, 0.f, 0.f};
#pragma unroll
        for (int kc = 0; kc < 7; ++kc) {
            s8v ap = *(const s8v*)&Ps[(w * 16 + (l & 15)) * VPAD + kc * 32 + (l >> 4) * 8];
#pragma unroll
            for (int n = 0; n < 4; ++n) {
                s8v bv = *(const s8v*)&Vt[(n * 16 + (l & 15)) * VPAD + kc * 32 + (l >> 4) * 8];
                oacc[n] = __builtin_amdgcn_mfma_f32_16x16x32_bf16(ap, bv, oacc[n], 0, 0, 0);
            }
        }
#pragma unroll
        for (int n = 0; n < 4; ++n) {
#pragma unroll
            for (int j = 0; j < 4; ++j) {
                int r = rbase + (l >> 4) * 4 + j;
                if (r < NN) {
                    float val = oacc[n][j] / sm[j];
                    ob[((size_t)(b * NN + r)) * DIM + h * 64 + n * 16 + (l & 15)] = f2b(val);
                }
            }
        }
    }
}

// ---------------- launch ----------------
extern "C" void kernel_launch(void* const* d_in, const int* in_sizes, int n_in,
                              void* d_out, int out_size, void* d_ws, size_t ws_size,
                              hipStream_t stream) {
    const float* x      = (const float*)d_in[0];
    const float* qkv_w  = (const float*)d_in[1];
    const float* qkv_b  = (const float*)d_in[2];
    const float* proj_w = (const float*)d_in[3];
    const float* proj_b = (const float*)d_in[4];
    const float* down_w = (const float*)d_in[5];
    const float* down_b = (const float*)d_in[6];
    const float* up_w   = (const float*)d_in[7];
    const float* up_b   = (const float*)d_in[8];
    float* out = (float*)d_out;

    char* ws = (char*)d_ws;
    size_t off = 0;
    unsigned short* xb      = (unsigned short*)(ws + off); off += (size_t)NT * DIM * 2;
    unsigned short* wcomb   = (unsigned short*)(ws + off); off += (size_t)NCOMB * DIM * 2;
    unsigned short* up_wb   = (unsigned short*)(ws + off); off += (size_t)2 * DIM * MID * 2;
    unsigned short* proj_wb = (unsigned short*)(ws + off); off += (size_t)DIM * DIM * 2;
    unsigned short* hbuf    = (unsigned short*)(ws + off); off += (size_t)NT * MID * 2;
    unsigned short* qkvbuf  = (unsigned short*)(ws + off); off += (size_t)NT * QKVC * 2;
    unsigned short* obuf    = xb;  // x dead after combined gemm; attn writes later

    cast_all<<<2048 + 2880, 256, 0, stream>>>(x, qkv_w, down_w, up_w, proj_w,
                                              xb, wcomb, up_wb, proj_wb);

    const int GM1 = (NT + 127) / 128;  // 99
    // fused qkv+down: qkvbuf (q scaled) + hbuf = tanh
    gemm64<0><<<GM1 * (NCOMB / 128), 256, 0, stream>>>(xb, wcomb, qkv_b, down_b,
                                                       NT, DIM, NCOMB / 128,
                                                       qkvbuf, hbuf, nullptr);
    // up: qkvbuf k/v cols += 0.8*(h @ up_w^T + b)
    gemm_up<<<GM1 * (2 * DIM / 128), 256, 0, stream>>>(hbuf, up_wb, up_b, NT, MID, 2 * DIM / 128,
                                                       qkvbuf);
    // attention
    attn_kernel<<<NB * HEADS, 256, 0, stream>>>(qkvbuf, obuf);
    // proj -> fp32 out
    gemm64<2><<<GM1 * (DIM / 128), 256, 0, stream>>>(obuf, proj_wb, proj_b, nullptr,
                                                     NT, DIM, DIM / 128,
                                                     nullptr, nullptr, out);
}

// Round 9
// 189.896 us; speedup vs baseline: 1.1514x; 1.1514x over previous
//
#include <hip/hip_runtime.h>
#include <hip/hip_bf16.h>
#include <stdint.h>

#define DIM   768
#define MID   256
#define HEADS 12
#define NB    64
#define NN    197
#define NT    (NB*NN)   // 12608
#define QKVC  2304      // 3*DIM
#define NCOMB 2560      // 3*DIM + MID

typedef __attribute__((ext_vector_type(4))) float f32x4;
typedef __attribute__((ext_vector_type(8))) short s8v;

__device__ __forceinline__ unsigned short f2b(float f) {
    union { float f; unsigned int u; } x; x.f = f;
    unsigned int u = x.u;
    unsigned int r = (u + 0x7FFFu + ((u >> 16) & 1u)) >> 16;
    return (unsigned short)r;
}
__device__ __forceinline__ float b2f(unsigned short s) {
    union { unsigned int u; float f; } x; x.u = ((unsigned int)s) << 16;
    return x.f;
}

__device__ __forceinline__ void gld_lds16(const void* g, void* l) {
    __builtin_amdgcn_global_load_lds(
        (const __attribute__((address_space(1))) unsigned int*)g,
        (__attribute__((address_space(3))) unsigned int*)l, 16, 0, 0);
}

// ------- merged casts: x (grid-stride) + all weights, one dispatch --------
__global__ void cast_all(const float* __restrict__ x,
                         const float* __restrict__ qkv_w,
                         const float* __restrict__ down_w,
                         const float* __restrict__ up_w,
                         const float* __restrict__ proj_w,
                         unsigned short* __restrict__ xb,
                         unsigned short* __restrict__ o_comb,
                         unsigned short* __restrict__ o_up,
                         unsigned short* __restrict__ o_proj) {
    int blk = blockIdx.x;
    if (blk < 2048) {
        const int n4 = NT * DIM / 4;
        for (int i = blk * 256 + threadIdx.x; i < n4; i += 2048 * 256) {
            float4 v = ((const float4*)x)[i];
            ushort4 o;
            o.x = f2b(v.x); o.y = f2b(v.y); o.z = f2b(v.z); o.w = f2b(v.w);
            ((ushort4*)xb)[i] = o;
        }
        return;
    }
    blk -= 2048;
    const float* in; unsigned short* out; int base;
    if (blk < 1728)      { in = qkv_w;  out = o_comb;              base = blk; }
    else if (blk < 1920) { in = down_w; out = o_comb + QKVC * DIM; base = blk - 1728; }
    else if (blk < 2304) { in = up_w;   out = o_up;                base = blk - 1920; }
    else                 { in = proj_w; out = o_proj;              base = blk - 2304; }
    int i = base * 256 + threadIdx.x;
    float4 v = ((const float4*)in)[i];
    ushort4 o;
    o.x = f2b(v.x); o.y = f2b(v.y); o.z = f2b(v.z); o.w = f2b(v.w);
    ((ushort4*)out)[i] = o;
}

// ------- 128^2 GEMM, BK=32, 3-buffer 2-deep prefetch, counted vmcnt -------
// (R6 verified-best GEMM; staging pointers strength-reduced, setprio MFMA.)
// EPI 0: combined qkv+down epilogue:
//        c <  QKVC: qkvbuf[r][c]    = (acc+qkv_b[c]) * (c<DIM ? 0.125 : 1)
//        c >= QKVC: hbuf[r][c-QKVC] = tanh(acc + down_b[c-QKVC])
// EPI 1: up RMW (coalesced short8): qkvbuf[r][768+c] += 0.8*(acc+bias)
// EPI 2: proj: outf[r][c] = acc+bias (fp32, already full-line)
template<int EPI>
__global__ __launch_bounds__(256) void gemm_bt(
    const unsigned short* __restrict__ A,
    const unsigned short* __restrict__ W,
    const float* __restrict__ bias0,
    const float* __restrict__ bias1,
    int M, int K, int GN,
    unsigned short* __restrict__ ob0,   // qkvbuf (EPI 0/1)
    unsigned short* __restrict__ ob1,   // hbuf   (EPI 0)
    float* __restrict__ outf)           // fp32 out (EPI 2)
{
    __shared__ __align__(16) unsigned short lds[3][2][128 * 32];  // 48 KiB
    const int tid = threadIdx.x;
    const int l = tid & 63;
    const int w = tid >> 6;
    const int wr = w >> 1, wc = w & 1;

    const int nwg = gridDim.x;
    const int orig = blockIdx.x;
    const int q8 = nwg >> 3, r8 = nwg & 7;
    const int xcd = orig & 7, slice = orig >> 3;
    const int wgid = (xcd < r8 ? xcd * (q8 + 1)
                               : r8 * (q8 + 1) + (xcd - r8) * q8) + slice;
    const int bm = wgid / GN;
    const int bn = wgid - bm * GN;

    f32x4 acc[4][4];
#pragma unroll
    for (int m = 0; m < 4; ++m)
#pragma unroll
        for (int n = 0; n < 4; ++n)
            acc[m][n] = (f32x4){0.f, 0.f, 0.f, 0.f};

    const int KT = K >> 5;

    // --- staging pointers: precomputed once, bumped +32 elems per stage ---
    const int src = (((tid & 3) ^ ((tid >> 3) & 3)) << 3);
    const int dst = ((tid & 3) << 3);
    const int dA0 = (tid >> 2) * 32 + dst;        // LDS dest offsets (elems)
    const int dA1 = dA0 + 64 * 32;
    int ra0 = bm * 128 + (tid >> 2);      if (ra0 > M - 1) ra0 = M - 1;
    int ra1 = bm * 128 + 64 + (tid >> 2); if (ra1 > M - 1) ra1 = M - 1;
    const int rb0 = bn * 128 + (tid >> 2);
    const int rb1 = rb0 + 64;
    const unsigned short* pa0 = A + (size_t)ra0 * K + src;
    const unsigned short* pa1 = A + (size_t)ra1 * K + src;
    const unsigned short* pb0 = W + (size_t)rb0 * K + src;
    const unsigned short* pb1 = W + (size_t)rb1 * K + src;

    auto stage = [&](int buf) {
        gld_lds16(pa0, &lds[buf][0][dA0]);
        gld_lds16(pb0, &lds[buf][1][dA0]);
        gld_lds16(pa1, &lds[buf][0][dA1]);
        gld_lds16(pb1, &lds[buf][1][dA1]);
        pa0 += 32; pa1 += 32; pb0 += 32; pb1 += 32;
    };

    // prologue: 2 tiles in flight (KT >= 8 for all our shapes)
    stage(0);
    stage(1);

    const int rsl = (((l >> 4) ^ ((l >> 1) & 3)) << 3);
    int cb = 0;   // buffer holding tile kt
    int sb = 2;   // buffer for tile kt+2
    for (int kt = 0; kt < KT; ++kt) {
        // tile kt resident: its 4 loads are the oldest; allow tile kt+1's 4 in flight
        if (kt + 1 < KT) asm volatile("s_waitcnt vmcnt(4)" ::: "memory");
        else             asm volatile("s_waitcnt vmcnt(0)" ::: "memory");
        __builtin_amdgcn_s_barrier();
        asm volatile("" ::: "memory");
        if (kt + 2 < KT) stage(sb);           // after barrier: WAR-safe vs kt-1 reads
        const unsigned short* la = lds[cb][0];
        const unsigned short* lb = lds[cb][1];
        s8v a[4], b[4];
#pragma unroll
        for (int m = 0; m < 4; ++m)
            a[m] = *(const s8v*)&la[(wr * 64 + m * 16 + (l & 15)) * 32 + rsl];
#pragma unroll
        for (int n = 0; n < 4; ++n)
            b[n] = *(const s8v*)&lb[(wc * 64 + n * 16 + (l & 15)) * 32 + rsl];
        __builtin_amdgcn_s_setprio(1);
#pragma unroll
        for (int m = 0; m < 4; ++m)
#pragma unroll
            for (int n = 0; n < 4; ++n)
                acc[m][n] = __builtin_amdgcn_mfma_f32_16x16x32_bf16(a[m], b[n], acc[m][n], 0, 0, 0);
        __builtin_amdgcn_s_setprio(0);
        cb = (cb == 2) ? 0 : cb + 1;
        sb = (sb == 2) ? 0 : sb + 1;
    }
    // all loads drained (vmcnt(0) on last iter); sync before LDS reuse in epilogue
    __syncthreads();

    if (EPI == 0) {
        // combined qkv+down epilogue: coalesced via wave-private LDS transpose
        unsigned short* stg = ((unsigned short*)lds) + w * (16 * 68);
        const int C0 = bn * 128 + wc * 64;
        const bool ish = (C0 >= QKVC);       // block/wave-uniform (64-col granules)
#pragma unroll
        for (int mq = 0; mq < 4; ++mq) {
#pragma unroll
            for (int n = 0; n < 4; ++n) {
                int c = C0 + n * 16 + (l & 15);
                float bi = ish ? bias1[c - QKVC] : bias0[c];
                float sc2 = (c < DIM) ? 0.125f : 1.0f;
#pragma unroll
                for (int j = 0; j < 4; ++j) {
                    float v = acc[mq][n][j] + bi;
                    v = ish ? tanhf(v) : v * sc2;
                    stg[((l >> 4) * 4 + j) * 68 + n * 16 + (l & 15)] = f2b(v);
                }
            }
#pragma unroll
            for (int p = 0; p < 2; ++p) {
                int rr2 = p * 8 + (l >> 3);
                int r = bm * 128 + wr * 64 + mq * 16 + rr2;
                s8v v = *(const s8v*)&stg[rr2 * 68 + (l & 7) * 8];
                if (r < M) {
                    if (!ish) *(s8v*)&ob0[(size_t)r * QKVC + C0 + (l & 7) * 8] = v;
                    else      *(s8v*)&ob1[(size_t)r * MID + (C0 - QKVC) + (l & 7) * 8] = v;
                }
            }
        }
    } else if (EPI == 1) {
        // coalesced RMW epilogue via wave-private LDS transpose
        unsigned short* stg = ((unsigned short*)lds) + w * (16 * 68);
        const int C0 = bn * 128 + wc * 64;
#pragma unroll
        for (int mq = 0; mq < 4; ++mq) {
#pragma unroll
            for (int n = 0; n < 4; ++n) {
                int c = C0 + n * 16 + (l & 15);
                float bi = bias0[c];
#pragma unroll
                for (int j = 0; j < 4; ++j)
                    stg[((l >> 4) * 4 + j) * 68 + n * 16 + (l & 15)] =
                        f2b(0.8f * (acc[mq][n][j] + bi));
            }
#pragma unroll
            for (int p = 0; p < 2; ++p) {
                int rr2 = p * 8 + (l >> 3);
                int r = bm * 128 + wr * 64 + mq * 16 + rr2;
                if (r < M) {
                    size_t base = (size_t)r * QKVC + DIM + C0 + (l & 7) * 8;
                    s8v add = *(const s8v*)&stg[rr2 * 68 + (l & 7) * 8];
                    s8v old = *(const s8v*)&ob0[base];
                    s8v res;
#pragma unroll
                    for (int i = 0; i < 8; ++i)
                        res[i] = (short)f2b(b2f((unsigned short)old[i]) +
                                            b2f((unsigned short)add[i]));
                    *(s8v*)&ob0[base] = res;
                }
            }
        }
    } else {
#pragma unroll
        for (int n = 0; n < 4; ++n) {
            int c = bn * 128 + wc * 64 + n * 16 + (l & 15);
            float bi = bias0[c];
#pragma unroll
            for (int m = 0; m < 4; ++m) {
#pragma unroll
                for (int j = 0; j < 4; ++j) {
                    int r = bm * 128 + wr * 64 + m * 16 + (l >> 4) * 4 + j;
                    if (r >= M) continue;
                    outf[(size_t)r * DIM + c] = acc[m][n][j] + bi;
                }
            }
        }
    }
}

// ---------------- attention: one block per (b,h), strided qkv layout -------
// Ps shrunk to a wave-private 16x40 chunk (softmax-exp fused into PV loop):
// LDS 87.4 KiB -> 62 KiB => 2 blocks/CU instead of 1.
#define NKV  224
#define VPAD 232
#define PSP  40    // 80 B row stride: 16B-aligned for b128 reads, low conflicts

__global__ __launch_bounds__(256) void attn_kernel(
    const unsigned short* __restrict__ qkv,
    unsigned short* __restrict__ ob)
{
    __shared__ __align__(16) unsigned short Ks[NKV * 64];       // 28 KiB
    __shared__ __align__(16) unsigned short Vt[64 * VPAD];      // 29 KiB
    __shared__ __align__(16) unsigned short Ps[4][16][PSP];     // 5 KiB, wave-private

    const int tid = threadIdx.x;
    const int l = tid & 63;
    const int w = tid >> 6;
    const int bh = blockIdx.x;
    const int b = bh / HEADS, h = bh - b * HEADS;
    const unsigned short* qp = qkv + (size_t)(b * NN) * QKVC + h * 64;
    const unsigned short* kp = qp + DIM;
    const unsigned short* vp = qp + 2 * DIM;

    const s8v zer = (s8v){0, 0, 0, 0, 0, 0, 0, 0};

    for (int e = tid; e < NKV * 8; e += 256) {
        int r = e >> 3, ch = e & 7;
        int idx = (r * 64 + ch * 8) ^ ((r & 7) << 3);
        s8v val = (r < NN) ? *(const s8v*)&kp[(size_t)r * QKVC + ch * 8] : zer;
        *(s8v*)&Ks[idx] = val;
    }
    for (int e = tid; e < NKV * 8; e += 256) {
        int r = e >> 3, ch = e & 7;
        s8v val = (r < NN) ? *(const s8v*)&vp[(size_t)r * QKVC + ch * 8] : zer;
#pragma unroll
        for (int i = 0; i < 8; ++i)
            Vt[(ch * 8 + i) * VPAD + r] = (unsigned short)val[i];
    }
    __syncthreads();

    unsigned short* psw = &Ps[w][0][0];   // wave-private P chunk

    for (int qc = 0; qc < 4; ++qc) {
        const int rbase = qc * 64 + w * 16;
        s8v aq[2];
#pragma unroll
        for (int kc = 0; kc < 2; ++kc) {
            int r = rbase + (l & 15); if (r > NN - 1) r = NN - 1;
            aq[kc] = *(const s8v*)&qp[(size_t)r * QKVC + kc * 32 + (l >> 4) * 8];
        }
        f32x4 sacc[14];
#pragma unroll
        for (int t = 0; t < 14; ++t) sacc[t] = (f32x4){0.f, 0.f, 0.f, 0.f};
#pragma unroll
        for (int t = 0; t < 14; ++t) {
            int col = t * 16 + (l & 15);
#pragma unroll
            for (int kc = 0; kc < 2; ++kc) {
                int idx = (col * 64 + kc * 32 + (l >> 4) * 8) ^ ((col & 7) << 3);
                s8v bk = *(const s8v*)&Ks[idx];
                sacc[t] = __builtin_amdgcn_mfma_f32_16x16x32_bf16(aq[kc], bk, sacc[t], 0, 0, 0);
            }
        }
        float mx[4] = {-1e30f, -1e30f, -1e30f, -1e30f};
#pragma unroll
        for (int t = 0; t < 14; ++t) {
            int col = t * 16 + (l & 15);
            if (col < NN) {
#pragma unroll
                for (int j = 0; j < 4; ++j) mx[j] = fmaxf(mx[j], sacc[t][j]);
            }
        }
#pragma unroll
        for (int j = 0; j < 4; ++j)
#pragma unroll
            for (int off = 1; off < 16; off <<= 1)
                mx[j] = fmaxf(mx[j], __shfl_xor(mx[j], off, 64));

        // ---- fused softmax-exp + PV: per 32-col chunk, wave-local Ps ----
        float sm[4] = {0.f, 0.f, 0.f, 0.f};
        f32x4 oacc[4];
#pragma unroll
        for (int n = 0; n < 4; ++n) oacc[n] = (f32x4){0.f, 0.f, 0.f, 0.f};
#pragma unroll
        for (int kc = 0; kc < 7; ++kc) {
#pragma unroll
            for (int th = 0; th < 2; ++th) {
                const int t = kc * 2 + th;
                int col = t * 16 + (l & 15);
#pragma unroll
                for (int j = 0; j < 4; ++j) {
                    float p = (col < NN) ? __expf(sacc[t][j] - mx[j]) : 0.f;
                    sm[j] += p;
                    psw[((l >> 4) * 4 + j) * PSP + th * 16 + (l & 15)] = f2b(p);
                }
            }
            // wave-local write->read: compiler inserts lgkmcnt
            s8v ap = *(const s8v*)&psw[(l & 15) * PSP + (l >> 4) * 8];
#pragma unroll
            for (int n = 0; n < 4; ++n) {
                s8v bv = *(const s8v*)&Vt[(n * 16 + (l & 15)) * VPAD + kc * 32 + (l >> 4) * 8];
                oacc[n] = __builtin_amdgcn_mfma_f32_16x16x32_bf16(ap, bv, oacc[n], 0, 0, 0);
            }
        }
#pragma unroll
        for (int j = 0; j < 4; ++j)
#pragma unroll
            for (int off = 1; off < 16; off <<= 1)
                sm[j] += __shfl_xor(sm[j], off, 64);

#pragma unroll
        for (int n = 0; n < 4; ++n) {
#pragma unroll
            for (int j = 0; j < 4; ++j) {
                int r = rbase + (l >> 4) * 4 + j;
                if (r < NN) {
                    float val = oacc[n][j] / sm[j];
                    ob[((size_t)(b * NN + r)) * DIM + h * 64 + n * 16 + (l & 15)] = f2b(val);
                }
            }
        }
    }
}

// ---------------- launch ----------------
extern "C" void kernel_launch(void* const* d_in, const int* in_sizes, int n_in,
                              void* d_out, int out_size, void* d_ws, size_t ws_size,
                              hipStream_t stream) {
    const float* x      = (const float*)d_in[0];
    const float* qkv_w  = (const float*)d_in[1];
    const float* qkv_b  = (const float*)d_in[2];
    const float* proj_w = (const float*)d_in[3];
    const float* proj_b = (const float*)d_in[4];
    const float* down_w = (const float*)d_in[5];
    const float* down_b = (const float*)d_in[6];
    const float* up_w   = (const float*)d_in[7];
    const float* up_b   = (const float*)d_in[8];
    float* out = (float*)d_out;

    char* ws = (char*)d_ws;
    size_t off = 0;
    unsigned short* xb      = (unsigned short*)(ws + off); off += (size_t)NT * DIM * 2;
    unsigned short* wcomb   = (unsigned short*)(ws + off); off += (size_t)NCOMB * DIM * 2;
    unsigned short* up_wb   = (unsigned short*)(ws + off); off += (size_t)2 * DIM * MID * 2;
    unsigned short* proj_wb = (unsigned short*)(ws + off); off += (size_t)DIM * DIM * 2;
    unsigned short* hbuf    = (unsigned short*)(ws + off); off += (size_t)NT * MID * 2;
    unsigned short* qkvbuf  = (unsigned short*)(ws + off); off += (size_t)NT * QKVC * 2;
    unsigned short* obuf    = xb;  // x dead after combined gemm; attn writes later

    cast_all<<<2048 + 2880, 256, 0, stream>>>(x, qkv_w, down_w, up_w, proj_w,
                                              xb, wcomb, up_wb, proj_wb);

    const int GM1 = (NT + 127) / 128;  // 99
    // fused qkv+down: qkvbuf (q scaled) + hbuf = tanh
    gemm_bt<0><<<GM1 * (NCOMB / 128), 256, 0, stream>>>(xb, wcomb, qkv_b, down_b,
                                                        NT, DIM, NCOMB / 128,
                                                        qkvbuf, hbuf, nullptr);
    // up: qkvbuf k/v cols += 0.8*(h @ up_w^T + b)
    gemm_bt<1><<<GM1 * (2 * DIM / 128), 256, 0, stream>>>(hbuf, up_wb, up_b, nullptr,
                                                          NT, MID, 2 * DIM / 128,
                                                          qkvbuf, nullptr, nullptr);
    // attention
    attn_kernel<<<NB * HEADS, 256, 0, stream>>>(qkvbuf, obuf);
    // proj -> fp32 out
    gemm_bt<2><<<GM1 * (DIM / 128), 256, 0, stream>>>(obuf, proj_wb, proj_b, nullptr,
                                                      NT, DIM, DIM / 128,
                                                      nullptr, nullptr, out);
}